// Round 2
// baseline (14010.004 us; speedup 1.0000x reference)
//
#include <hip/hip_runtime.h>
#include <math.h>

// ---------------------------------------------------------------------------
// PointNet++ part-seg forward. All features stored point-major: row = point,
// C contiguous floats per row. B=4, N=8192 fixed by the problem.
// ---------------------------------------------------------------------------

// ---------------- workspace layout (bytes) ----------------
static constexpr size_t O_FEATS0 = 0;                    // (4*8192, 64)  f32
static constexpr size_t O_FEATS1 = 8388608;              // (4*2048, 128)
static constexpr size_t O_FEATS2 = 12582912;             // (4*1024, 256)
static constexpr size_t O_FP0OUT = 16777216;             // (4*2048, 512)
static constexpr size_t O_XYZ1   = 33554432;             // (4*2048, 3)
static constexpr size_t O_XYZ2   = 33652736;             // (4*1024, 3)
static constexpr size_t O_FPS1   = 33701888;             // (4*2048) int
static constexpr size_t O_FPS2   = 33734656;             // (4*1024) int
static constexpr size_t O_BALL1  = 33751040;             // (4*2048*32) int
static constexpr size_t O_BALL2  = 34799616;             // (4*1024*32) int
static constexpr size_t O_NN0I   = 35323904;             // (4*2048*3) int
static constexpr size_t O_NN0W   = 35422208;             // (4*2048*3) f32
static constexpr size_t O_NN1I   = 35520512;             // (4*8192*3) int
static constexpr size_t O_NN1W   = 35913728;             // (4*8192*3) f32
static constexpr size_t O_REG0   = 36306944;             // 67108864 scratch
static constexpr size_t O_REG1   = 103415808;            // 67108864 scratch
static constexpr size_t WS_NEED  = 170524672;

// ---------------- emb: xyz -> relu(bn(W2*relu(bn(W1*xyz)))) ----------------
__global__ __launch_bounds__(256) void emb_kernel(
    const float* __restrict__ xyz, const float* __restrict__ w1,
    const float* __restrict__ g1, const float* __restrict__ b1,
    const float* __restrict__ w2, const float* __restrict__ g2,
    const float* __restrict__ b2, float* __restrict__ out) {
  const int t = threadIdx.x;
  const int o = t & 63, pl = t >> 6;
  const int pt = blockIdx.x * 4 + pl;
  const float x0 = xyz[(size_t)pt * 3 + 0];
  const float x1 = xyz[(size_t)pt * 3 + 1];
  const float x2 = xyz[(size_t)pt * 3 + 2];
  const float SQ = sqrtf(1.0f + 1e-5f);
  float v = w1[o * 3 + 0] * x0 + w1[o * 3 + 1] * x1 + w1[o * 3 + 2] * x2;
  v = fmaxf(v * (g1[o] / SQ) + b1[o], 0.0f);
  __shared__ float h[4][64];
  h[pl][o] = v;
  __syncthreads();
  float acc = 0.0f;
  #pragma unroll 8
  for (int i = 0; i < 64; ++i) acc += w2[o * 64 + i] * h[pl][i];
  float y = fmaxf(acc * (g2[o] / SQ) + b2[o], 0.0f);
  out[(size_t)pt * 64 + o] = y;
}

// ---------------- farthest point sampling (latency-optimized) ----------------
// 256 threads (4 waves) per batch. The winner's coordinates are carried
// THROUGH the reductions so no dependent global/LDS center fetch is needed.
// One barrier per iteration via parity-double-buffered 4-entry LDS scratch.
template <int N, int NP>
__global__ __launch_bounds__(256, 1) void fps_kernel(
    const float* __restrict__ xyz, int* __restrict__ out) {
  constexpr int PPT = N / 256;
  const int b = blockIdx.x, t = threadIdx.x;
  const float* xb = xyz + (size_t)b * N * 3;
  __shared__ float sv[2][4], sx[2][4], sy[2][4], sz[2][4];
  __shared__ int si[2][4];
  float px[PPT], py[PPT], pz[PPT], dist[PPT];
  #pragma unroll
  for (int j = 0; j < PPT; ++j) {
    const int g = t * PPT + j;
    px[j] = xb[g * 3 + 0];
    py[j] = xb[g * 3 + 1];
    pz[j] = xb[g * 3 + 2];
    dist[j] = 1e10f;
  }
  const int wid = t >> 6, lane = t & 63;
  int far = 0;
  float ccx = xb[0], ccy = xb[1], ccz = xb[2];
  for (int it = 0; it < NP; ++it) {
    if (t == 0) out[(size_t)b * NP + it] = far;
    // ---- distance update + local argmax over PPT (tree, stable ties) ----
    float tv[PPT];
    #pragma unroll
    for (int j = 0; j < PPT; ++j) {
      const float dx = __fsub_rn(px[j], ccx);
      const float dy = __fsub_rn(py[j], ccy);
      const float dz = __fsub_rn(pz[j], ccz);
      const float d = __fadd_rn(__fadd_rn(__fmul_rn(dx, dx), __fmul_rn(dy, dy)),
                                __fmul_rn(dz, dz));
      const float nd = fminf(dist[j], d);
      dist[j] = nd;
      tv[j] = nd;
    }
    int tj[PPT];
    #pragma unroll
    for (int j = 0; j < PPT; ++j) tj[j] = j;
    #pragma unroll
    for (int w = PPT / 2; w >= 1; w >>= 1) {
      #pragma unroll
      for (int j = 0; j < w; ++j) {
        if (tv[j + w] > tv[j] || (tv[j + w] == tv[j] && tj[j + w] < tj[j])) {
          tv[j] = tv[j + w];
          tj[j] = tj[j + w];
        }
      }
    }
    float bv = tv[0];
    const int bjl = tj[0];
    // coords of local winner (static-index selects, no reg-array indexing)
    float bx = px[0], by = py[0], bz = pz[0];
    #pragma unroll
    for (int j = 1; j < PPT; ++j) {
      const bool w = (bjl == j);
      bx = w ? px[j] : bx;
      by = w ? py[j] : by;
      bz = w ? pz[j] : bz;
    }
    int bi = t * PPT + bjl;
    // ---- in-wave butterfly, coords ride along ----
    #pragma unroll
    for (int m = 32; m >= 1; m >>= 1) {
      const float ov = __shfl_xor(bv, m, 64);
      const int oi = __shfl_xor(bi, m, 64);
      const float ox = __shfl_xor(bx, m, 64);
      const float oy = __shfl_xor(by, m, 64);
      const float oz = __shfl_xor(bz, m, 64);
      if (ov > bv || (ov == bv && oi < bi)) {
        bv = ov; bi = oi; bx = ox; by = oy; bz = oz;
      }
    }
    const int p = it & 1;
    if (lane == 0) {
      sv[p][wid] = bv; si[p][wid] = bi;
      sx[p][wid] = bx; sy[p][wid] = by; sz[p][wid] = bz;
    }
    __syncthreads();
    // ---- every thread picks best of the 4 wave winners (deterministic) ----
    float v = sv[p][0];
    int wi = si[p][0];
    float nx = sx[p][0], ny = sy[p][0], nz = sz[p][0];
    #pragma unroll
    for (int wv = 1; wv < 4; ++wv) {
      const float v2 = sv[p][wv];
      const int i2 = si[p][wv];
      if (v2 > v || (v2 == v && i2 < wi)) {
        v = v2; wi = i2;
        nx = sx[p][wv]; ny = sy[p][wv]; nz = sz[p][wv];
      }
    }
    far = wi; ccx = nx; ccy = ny; ccz = nz;
  }
}

// ---------------- gather xyz by index ----------------
__global__ __launch_bounds__(256) void gatherxyz_kernel(
    const float* __restrict__ xyz, const int* __restrict__ idx,
    float* __restrict__ out, int sbits, int N) {
  const int id = blockIdx.x * 256 + threadIdx.x;
  const int b = id >> sbits;
  const int n = idx[id];
  out[(size_t)id * 3 + 0] = xyz[((size_t)b * N + n) * 3 + 0];
  out[(size_t)id * 3 + 1] = xyz[((size_t)b * N + n) * 3 + 1];
  out[(size_t)id * 3 + 2] = xyz[((size_t)b * N + n) * 3 + 2];
}

// ---------------- ball query: first 32 indices with d2 <= 1 ----------------
__global__ __launch_bounds__(256) void ball_kernel(
    const float* __restrict__ xyz, const float* __restrict__ ctr,
    int* __restrict__ out, int sbits, int N) {
  const int t = threadIdx.x;
  const int lane = t & 63, wid = t >> 6;
  const int wg = blockIdx.x * 4 + wid;   // global center id
  const int b = wg >> sbits;
  __shared__ int lists[4][32];
  const float cx = ctr[(size_t)wg * 3 + 0];
  const float cy = ctr[(size_t)wg * 3 + 1];
  const float cz = ctr[(size_t)wg * 3 + 2];
  const float an = __fadd_rn(__fadd_rn(__fmul_rn(cx, cx), __fmul_rn(cy, cy)),
                             __fmul_rn(cz, cz));
  int fill = 0;
  for (int ch = 0; ch < (N >> 6) && fill < 32; ++ch) {
    const int n = ch * 64 + lane;
    const float bx = xyz[((size_t)b * N + n) * 3 + 0];
    const float by = xyz[((size_t)b * N + n) * 3 + 1];
    const float bz = xyz[((size_t)b * N + n) * 3 + 2];
    const float bb = __fadd_rn(__fadd_rn(__fmul_rn(bx, bx), __fmul_rn(by, by)),
                               __fmul_rn(bz, bz));
    const float dot = __fadd_rn(__fadd_rn(__fmul_rn(cx, bx), __fmul_rn(cy, by)),
                                __fmul_rn(cz, bz));
    const float d2 = __fsub_rn(__fadd_rn(an, bb), __fmul_rn(2.0f, dot));
    const bool q = (d2 <= 1.0f);
    const unsigned long long mask = __ballot(q);
    if (q) {
      const int pos = fill + __popcll(mask & ((1ull << lane) - 1ull));
      if (pos < 32) lists[wid][pos] = n;
    }
    fill += (int)__popcll(mask);
  }
  __syncthreads();
  if (lane < 32) {
    int v = lists[wid][0];
    if (lane < fill) v = lists[wid][lane];
    out[(size_t)wg * 32 + lane] = v;
  }
}

// ---------------- grouped feature materialization ----------------
// row (chunk-local) -> [f[src]-f[ctr] (Cf) ; f[ctr] (Cf)]
__global__ __launch_bounds__(256) void groupmat_kernel(
    float* __restrict__ Xo, const float* __restrict__ f,
    const int* __restrict__ ball, const int* __restrict__ fps, int g0, int Cf,
    int c4bits, int sbits, int Npts) {
  const int id = blockIdx.x * 256 + threadIdx.x;
  const int c4mask = (1 << c4bits) - 1;
  const int row = id >> c4bits;
  const int col = (id & c4mask) * 4;
  const int gl = g0 + (row >> 5);
  const int k = row & 31;
  const int b = gl >> sbits;
  const int src = ball[(size_t)gl * 32 + k];
  const int ctr = fps[gl];
  const int C = Cf * 2;
  const float* fb = f + (size_t)b * Npts * Cf;
  float4 v;
  if (col < Cf) {
    const float4 a = *(const float4*)(fb + (size_t)src * Cf + col);
    const float4 c = *(const float4*)(fb + (size_t)ctr * Cf + col);
    v = make_float4(a.x - c.x, a.y - c.y, a.z - c.z, a.w - c.w);
  } else {
    v = *(const float4*)(fb + (size_t)ctr * Cf + (col - Cf));
  }
  *(float4*)(Xo + (size_t)row * C + col) = v;
}

// ---------------- generic 1x1 conv (GEMM) with BN/bias/ReLU epilogue -------
// Y[(m), o] = relu( (sum_i X[m,i] W[o,i] + bias[o]) * g[o]/sqrt(1+eps) + beta[o] )
__global__ __launch_bounds__(256) void conv_kernel(
    const float* __restrict__ X, const float* __restrict__ W,
    float* __restrict__ Y, int C, int O, const float* __restrict__ gamma,
    const float* __restrict__ beta, const float* __restrict__ bias, int relu) {
  __shared__ float Xs[16][132];
  __shared__ float Ws[16][132];
  const int t = threadIdx.x;
  const size_t m0 = (size_t)blockIdx.x * 128;
  const int o0 = blockIdx.y * 128;
  const int r0 = t >> 2;
  const int cq0 = (t & 3) * 4;
  const int mq = t & 15, nq = t >> 4;
  float acc[8][8];
  #pragma unroll
  for (int i = 0; i < 8; ++i)
    #pragma unroll
    for (int j = 0; j < 8; ++j) acc[i][j] = 0.0f;

  for (int kk = 0; kk < C; kk += 16) {
    const float4 xa = *(const float4*)(X + (m0 + r0) * C + kk + cq0);
    const float4 xb = *(const float4*)(X + (m0 + r0 + 64) * C + kk + cq0);
    const float4 wa = *(const float4*)(W + (size_t)(o0 + r0) * C + kk + cq0);
    const float4 wb = *(const float4*)(W + (size_t)(o0 + r0 + 64) * C + kk + cq0);
    __syncthreads();
    Xs[cq0 + 0][r0] = xa.x; Xs[cq0 + 1][r0] = xa.y;
    Xs[cq0 + 2][r0] = xa.z; Xs[cq0 + 3][r0] = xa.w;
    Xs[cq0 + 0][r0 + 64] = xb.x; Xs[cq0 + 1][r0 + 64] = xb.y;
    Xs[cq0 + 2][r0 + 64] = xb.z; Xs[cq0 + 3][r0 + 64] = xb.w;
    Ws[cq0 + 0][r0] = wa.x; Ws[cq0 + 1][r0] = wa.y;
    Ws[cq0 + 2][r0] = wa.z; Ws[cq0 + 3][r0] = wa.w;
    Ws[cq0 + 0][r0 + 64] = wb.x; Ws[cq0 + 1][r0 + 64] = wb.y;
    Ws[cq0 + 2][r0 + 64] = wb.z; Ws[cq0 + 3][r0 + 64] = wb.w;
    __syncthreads();
    #pragma unroll
    for (int k = 0; k < 16; ++k) {
      const float4 a0 = *(const float4*)&Xs[k][mq * 8];
      const float4 a1 = *(const float4*)&Xs[k][mq * 8 + 4];
      const float4 b0 = *(const float4*)&Ws[k][nq * 8];
      const float4 b1 = *(const float4*)&Ws[k][nq * 8 + 4];
      const float am[8] = {a0.x, a0.y, a0.z, a0.w, a1.x, a1.y, a1.z, a1.w};
      const float bm[8] = {b0.x, b0.y, b0.z, b0.w, b1.x, b1.y, b1.z, b1.w};
      #pragma unroll
      for (int i = 0; i < 8; ++i)
        #pragma unroll
        for (int j = 0; j < 8; ++j) acc[i][j] += am[i] * bm[j];
    }
  }

  const float SQ = sqrtf(1.0f + 1e-5f);
  float s[8], sh[8];
  #pragma unroll
  for (int j = 0; j < 8; ++j) {
    const int o = o0 + nq * 8 + j;
    const float sc = gamma ? (gamma[o] / SQ) : 1.0f;
    float bb = beta ? beta[o] : 0.0f;
    if (bias) bb = bb + bias[o] * sc;
    s[j] = sc; sh[j] = bb;
  }
  #pragma unroll
  for (int i = 0; i < 8; ++i) {
    float y[8];
    #pragma unroll
    for (int j = 0; j < 8; ++j) {
      float v = acc[i][j] * s[j] + sh[j];
      y[j] = relu ? fmaxf(v, 0.0f) : v;
    }
    const size_t off = (m0 + mq * 8 + i) * O + o0 + nq * 8;
    *(float4*)(Y + off) = make_float4(y[0], y[1], y[2], y[3]);
    *(float4*)(Y + off + 4) = make_float4(y[4], y[5], y[6], y[7]);
  }
}

// ---------------- segmented max over 32 samples ----------------
__global__ __launch_bounds__(256) void segmax_kernel(
    const float* __restrict__ Y, float* __restrict__ F, int O, int obits) {
  const int id = blockIdx.x * 256 + threadIdx.x;
  const int g = id >> obits;
  const int o = id & (O - 1);
  float m = -3.4e38f;
  #pragma unroll 8
  for (int k = 0; k < 32; ++k)
    m = fmaxf(m, Y[((size_t)g * 32 + k) * O + o]);
  F[(size_t)g * O + o] = m;
}

// ---------------- 3-NN search (stable, strict <) ----------------
__global__ __launch_bounds__(256) void nn3_kernel(
    const float* __restrict__ txyz, const float* __restrict__ sxyz,
    int* __restrict__ oi, float* __restrict__ ow, int s1bits, int S2) {
  __shared__ float ss[6144];
  const int t = threadIdx.x;
  const int row = blockIdx.x * 256 + t;
  const int b = row >> s1bits;
  for (int i = t; i < S2 * 3; i += 256) ss[i] = sxyz[(size_t)b * S2 * 3 + i];
  __syncthreads();
  const float ax = txyz[(size_t)row * 3 + 0];
  const float ay = txyz[(size_t)row * 3 + 1];
  const float az = txyz[(size_t)row * 3 + 2];
  const float an = __fadd_rn(__fadd_rn(__fmul_rn(ax, ax), __fmul_rn(ay, ay)),
                             __fmul_rn(az, az));
  float d0 = 3.4e38f, d1 = 3.4e38f, d2v = 3.4e38f;
  int i0 = 0, i1 = 0, i2 = 0;
  for (int j = 0; j < S2; ++j) {
    const float bx = ss[j * 3 + 0], by = ss[j * 3 + 1], bz = ss[j * 3 + 2];
    const float bb = __fadd_rn(__fadd_rn(__fmul_rn(bx, bx), __fmul_rn(by, by)),
                               __fmul_rn(bz, bz));
    const float dot = __fadd_rn(__fadd_rn(__fmul_rn(ax, bx), __fmul_rn(ay, by)),
                                __fmul_rn(az, bz));
    const float dd = __fsub_rn(__fadd_rn(an, bb), __fmul_rn(2.0f, dot));
    if (dd < d0) {
      d2v = d1; i2 = i1; d1 = d0; i1 = i0; d0 = dd; i0 = j;
    } else if (dd < d1) {
      d2v = d1; i2 = i1; d1 = dd; i1 = j;
    } else if (dd < d2v) {
      d2v = dd; i2 = j;
    }
  }
  const float r0 = 1.0f / (d0 + 1e-8f);
  const float r1 = 1.0f / (d1 + 1e-8f);
  const float r2 = 1.0f / (d2v + 1e-8f);
  const float sum = __fadd_rn(__fadd_rn(r0, r1), r2);
  oi[(size_t)row * 3 + 0] = i0;
  oi[(size_t)row * 3 + 1] = i1;
  oi[(size_t)row * 3 + 2] = i2;
  ow[(size_t)row * 3 + 0] = r0 / sum;
  ow[(size_t)row * 3 + 1] = r1 / sum;
  ow[(size_t)row * 3 + 2] = r2 / sum;
}

// ---------------- weighted 3-point interpolation into concat columns -------
__global__ __launch_bounds__(256) void interp_kernel(
    float* __restrict__ dst, int CT, int c0, const float* __restrict__ src,
    const int* __restrict__ idx, const float* __restrict__ w, int csbits,
    int s1bits, int S2) {
  const int id = blockIdx.x * 256 + threadIdx.x;
  const int row = id >> csbits;
  const int c4 = (id & ((1 << csbits) - 1)) * 4;
  const int Cs = 4 << csbits;
  const int b = row >> s1bits;
  const int j0 = idx[(size_t)row * 3 + 0];
  const int j1 = idx[(size_t)row * 3 + 1];
  const int j2 = idx[(size_t)row * 3 + 2];
  const float w0 = w[(size_t)row * 3 + 0];
  const float w1 = w[(size_t)row * 3 + 1];
  const float w2 = w[(size_t)row * 3 + 2];
  const float4 f0 = *(const float4*)(src + ((size_t)b * S2 + j0) * Cs + c4);
  const float4 f1 = *(const float4*)(src + ((size_t)b * S2 + j1) * Cs + c4);
  const float4 f2 = *(const float4*)(src + ((size_t)b * S2 + j2) * Cs + c4);
  float4 v;
  v.x = f0.x * w0 + f1.x * w1 + f2.x * w2;
  v.y = f0.y * w0 + f1.y * w1 + f2.y * w2;
  v.z = f0.z * w0 + f1.z * w1 + f2.z * w2;
  v.w = f0.w * w0 + f1.w * w1 + f2.w * w2;
  *(float4*)(dst + (size_t)row * CT + c0 + c4) = v;
}

// ---------------- copy columns into concat buffer ----------------
__global__ __launch_bounds__(256) void copycols_kernel(
    float* __restrict__ dst, int CT, int c0, const float* __restrict__ src,
    int csbits) {
  const int id = blockIdx.x * 256 + threadIdx.x;
  const int row = id >> csbits;
  const int c4 = (id & ((1 << csbits) - 1)) * 4;
  const int Cs = 4 << csbits;
  const float4 v = *(const float4*)(src + (size_t)row * Cs + c4);
  *(float4*)(dst + (size_t)row * CT + c0 + c4) = v;
}

// ---------------- final 128->8 conv + bias, point-major out ----------------
__global__ __launch_bounds__(256) void outfinal_kernel(
    const float* __restrict__ X, const float* __restrict__ Wt,
    const float* __restrict__ bias, float* __restrict__ out) {
  __shared__ float Xs[32][132];
  const int t = threadIdx.x;
  const int p0 = blockIdx.x * 32;
  #pragma unroll
  for (int q = 0; q < 4; ++q) {
    const int id = t + q * 256;
    const int r = id >> 5, c4 = (id & 31) * 4;
    const float4 v = *(const float4*)(X + (size_t)(p0 + r) * 128 + c4);
    Xs[r][c4 + 0] = v.x; Xs[r][c4 + 1] = v.y;
    Xs[r][c4 + 2] = v.z; Xs[r][c4 + 3] = v.w;
  }
  __syncthreads();
  const int p = t >> 3, o = t & 7;
  float acc = 0.0f;
  #pragma unroll 8
  for (int i = 0; i < 128; ++i) acc += Wt[o * 128 + i] * Xs[p][i];
  out[(size_t)(p0 + p) * 8 + o] = acc + bias[o];
}

// ---------------------------------------------------------------------------
extern "C" void kernel_launch(void* const* d_in, const int* in_sizes, int n_in,
                              void* d_out, int out_size, void* d_ws,
                              size_t ws_size, hipStream_t stream) {
  const float* x       = (const float*)d_in[0];
  const float* w_emb1  = (const float*)d_in[1];
  const float* g_emb1  = (const float*)d_in[2];
  const float* be_emb1 = (const float*)d_in[3];
  const float* w_emb2  = (const float*)d_in[4];
  const float* g_emb2  = (const float*)d_in[5];
  const float* be_emb2 = (const float*)d_in[6];
  const float* l0_w1 = (const float*)d_in[7];
  const float* l0_g1 = (const float*)d_in[8];
  const float* l0_b1 = (const float*)d_in[9];
  const float* l0_w2 = (const float*)d_in[10];
  const float* l0_g2 = (const float*)d_in[11];
  const float* l0_b2 = (const float*)d_in[12];
  const float* l1_w1 = (const float*)d_in[13];
  const float* l1_g1 = (const float*)d_in[14];
  const float* l1_b1 = (const float*)d_in[15];
  const float* l1_w2 = (const float*)d_in[16];
  const float* l1_g2 = (const float*)d_in[17];
  const float* l1_b2 = (const float*)d_in[18];
  const float* f0_w1 = (const float*)d_in[19];
  const float* f0_g1 = (const float*)d_in[20];
  const float* f0_b1 = (const float*)d_in[21];
  const float* f0_w2 = (const float*)d_in[22];
  const float* f0_g2 = (const float*)d_in[23];
  const float* f0_b2 = (const float*)d_in[24];
  const float* f1_w1 = (const float*)d_in[25];
  const float* f1_g1 = (const float*)d_in[26];
  const float* f1_b1 = (const float*)d_in[27];
  const float* f1_w2 = (const float*)d_in[28];
  const float* f1_g2 = (const float*)d_in[29];
  const float* f1_b2 = (const float*)d_in[30];
  const float* c1_w    = (const float*)d_in[31];
  const float* c1_bias = (const float*)d_in[32];
  const float* c1_g    = (const float*)d_in[33];
  const float* c1_beta = (const float*)d_in[34];
  const float* c2_w    = (const float*)d_in[35];
  const float* c2_bias = (const float*)d_in[36];
  const float* c2_g    = (const float*)d_in[37];
  const float* c2_beta = (const float*)d_in[38];
  const float* out_w    = (const float*)d_in[39];
  const float* out_bias = (const float*)d_in[40];

  if (ws_size < WS_NEED) return;  // cannot run without scratch

  char* ws = (char*)d_ws;
  float* feats0 = (float*)(ws + O_FEATS0);
  float* feats1 = (float*)(ws + O_FEATS1);
  float* feats2 = (float*)(ws + O_FEATS2);
  float* fp0out = (float*)(ws + O_FP0OUT);
  float* xyz1   = (float*)(ws + O_XYZ1);
  float* xyz2   = (float*)(ws + O_XYZ2);
  int*   fps1   = (int*)(ws + O_FPS1);
  int*   fps2   = (int*)(ws + O_FPS2);
  int*   ball1  = (int*)(ws + O_BALL1);
  int*   ball2  = (int*)(ws + O_BALL2);
  int*   nn0i   = (int*)(ws + O_NN0I);
  float* nn0w   = (float*)(ws + O_NN0W);
  int*   nn1i   = (int*)(ws + O_NN1I);
  float* nn1w   = (float*)(ws + O_NN1W);
  float* REG0   = (float*)(ws + O_REG0);
  float* REG1   = (float*)(ws + O_REG1);
  float* outp   = (float*)d_out;
  hipStream_t s = stream;

  // ---- embedding MLP: (B*8192, 64) ----
  emb_kernel<<<8192, 256, 0, s>>>(x, w_emb1, g_emb1, be_emb1, w_emb2, g_emb2,
                                  be_emb2, feats0);

  // ---- SA layer 1 ----
  fps_kernel<8192, 2048><<<4, 256, 0, s>>>(x, fps1);
  gatherxyz_kernel<<<32, 256, 0, s>>>(x, fps1, xyz1, 11, 8192);
  ball_kernel<<<2048, 256, 0, s>>>(x, xyz1, ball1, 11, 8192);
  for (int c = 0; c < 2; ++c) {
    groupmat_kernel<<<16384, 256, 0, s>>>(REG0, feats0, ball1, fps1, c * 4096,
                                          64, 5, 11, 8192);
    conv_kernel<<<dim3(1024, 1), 256, 0, s>>>(REG0, l0_w1, REG1, 128, 128,
                                              l0_g1, l0_b1, nullptr, 1);
    conv_kernel<<<dim3(1024, 1), 256, 0, s>>>(REG1, l0_w2, REG0, 128, 128,
                                              l0_g2, l0_b2, nullptr, 1);
    segmax_kernel<<<2048, 256, 0, s>>>(REG0, feats1 + (size_t)c * 4096 * 128,
                                       128, 7);
  }

  // ---- SA layer 2 ----
  fps_kernel<2048, 1024><<<4, 256, 0, s>>>(xyz1, fps2);
  gatherxyz_kernel<<<16, 256, 0, s>>>(xyz1, fps2, xyz2, 10, 2048);
  ball_kernel<<<1024, 256, 0, s>>>(xyz1, xyz2, ball2, 10, 2048);
  for (int c = 0; c < 2; ++c) {
    groupmat_kernel<<<16384, 256, 0, s>>>(REG0, feats1, ball2, fps2, c * 2048,
                                          128, 6, 10, 2048);
    conv_kernel<<<dim3(512, 2), 256, 0, s>>>(REG0, l1_w1, REG1, 256, 256,
                                             l1_g1, l1_b1, nullptr, 1);
    conv_kernel<<<dim3(512, 2), 256, 0, s>>>(REG1, l1_w2, REG0, 256, 256,
                                             l1_g2, l1_b2, nullptr, 1);
    segmax_kernel<<<2048, 256, 0, s>>>(REG0, feats2 + (size_t)c * 2048 * 256,
                                       256, 8);
  }

  // ---- feature propagation 0: 1024 -> 2048 points ----
  nn3_kernel<<<32, 256, 0, s>>>(xyz1, xyz2, nn0i, nn0w, 11, 1024);
  copycols_kernel<<<1024, 256, 0, s>>>(REG0, 384, 0, feats1, 5);
  interp_kernel<<<2048, 256, 0, s>>>(REG0, 384, 128, feats2, nn0i, nn0w, 6, 11,
                                     1024);
  conv_kernel<<<dim3(64, 2), 256, 0, s>>>(REG0, f0_w1, REG1, 384, 256, f0_g1,
                                          f0_b1, nullptr, 1);
  conv_kernel<<<dim3(64, 4), 256, 0, s>>>(REG1, f0_w2, fp0out, 256, 512, f0_g2,
                                          f0_b2, nullptr, 1);

  // ---- feature propagation 1 + head, chunked per batch ----
  nn3_kernel<<<128, 256, 0, s>>>(x, xyz1, nn1i, nn1w, 13, 2048);
  for (int b = 0; b < 4; ++b) {
    copycols_kernel<<<512, 256, 0, s>>>(REG0, 576, 0,
                                        feats0 + (size_t)b * 8192 * 64, 4);
    interp_kernel<<<4096, 256, 0, s>>>(REG0, 576, 64,
                                       fp0out + (size_t)b * 2048 * 512,
                                       nn1i + (size_t)b * 8192 * 3,
                                       nn1w + (size_t)b * 8192 * 3, 7, 13,
                                       2048);
    conv_kernel<<<dim3(64, 4), 256, 0, s>>>(REG0, f1_w1, REG1, 576, 512, f1_g1,
                                            f1_b1, nullptr, 1);
    conv_kernel<<<dim3(64, 8), 256, 0, s>>>(REG1, f1_w2, REG0, 512, 1024,
                                            f1_g2, f1_b2, nullptr, 1);
    conv_kernel<<<dim3(64, 4), 256, 0, s>>>(REG0, c1_w, REG1, 1024, 512, c1_g,
                                            c1_beta, c1_bias, 1);
    conv_kernel<<<dim3(64, 1), 256, 0, s>>>(REG1, c2_w, REG0, 512, 128, c2_g,
                                            c2_beta, c2_bias, 1);
    outfinal_kernel<<<256, 256, 0, s>>>(REG0, out_w, out_bias,
                                        outp + (size_t)b * 8192 * 8);
  }
}

// Round 3
// 6576.747 us; speedup vs baseline: 2.1302x; 2.1302x over previous
//
#include <hip/hip_runtime.h>
#include <math.h>

// ---------------------------------------------------------------------------
// PointNet++ part-seg forward. All features stored point-major: row = point,
// C contiguous floats per row. B=4, N=8192 fixed by the problem.
// ---------------------------------------------------------------------------

// ---------------- workspace layout (bytes) ----------------
static constexpr size_t O_FEATS0 = 0;                    // (4*8192, 64)  f32
static constexpr size_t O_FEATS1 = 8388608;              // (4*2048, 128)
static constexpr size_t O_FEATS2 = 12582912;             // (4*1024, 256)
static constexpr size_t O_FP0OUT = 16777216;             // (4*2048, 512)
static constexpr size_t O_XYZ1   = 33554432;             // (4*2048, 3)
static constexpr size_t O_XYZ2   = 33652736;             // (4*1024, 3)
static constexpr size_t O_FPS1   = 33701888;             // (4*2048) int
static constexpr size_t O_FPS2   = 33734656;             // (4*1024) int
static constexpr size_t O_BALL1  = 33751040;             // (4*2048*32) int
static constexpr size_t O_BALL2  = 34799616;             // (4*1024*32) int
static constexpr size_t O_NN0I   = 35323904;             // (4*2048*3) int
static constexpr size_t O_NN0W   = 35422208;             // (4*2048*3) f32
static constexpr size_t O_NN1I   = 35520512;             // (4*8192*3) int
static constexpr size_t O_NN1W   = 35913728;             // (4*8192*3) f32
static constexpr size_t O_REG0   = 36306944;             // 67108864 scratch
static constexpr size_t O_REG1   = 103415808;            // 67108864 scratch
static constexpr size_t WS_NEED  = 170524672;

// ---------------- emb: xyz -> relu(bn(W2*relu(bn(W1*xyz)))) ----------------
__global__ __launch_bounds__(256) void emb_kernel(
    const float* __restrict__ xyz, const float* __restrict__ w1,
    const float* __restrict__ g1, const float* __restrict__ b1,
    const float* __restrict__ w2, const float* __restrict__ g2,
    const float* __restrict__ b2, float* __restrict__ out) {
  const int t = threadIdx.x;
  const int o = t & 63, pl = t >> 6;
  const int pt = blockIdx.x * 4 + pl;
  const float x0 = xyz[(size_t)pt * 3 + 0];
  const float x1 = xyz[(size_t)pt * 3 + 1];
  const float x2 = xyz[(size_t)pt * 3 + 2];
  const float SQ = sqrtf(1.0f + 1e-5f);
  float v = w1[o * 3 + 0] * x0 + w1[o * 3 + 1] * x1 + w1[o * 3 + 2] * x2;
  v = fmaxf(v * (g1[o] / SQ) + b1[o], 0.0f);
  __shared__ float h[4][64];
  h[pl][o] = v;
  __syncthreads();
  float acc = 0.0f;
  #pragma unroll 8
  for (int i = 0; i < 64; ++i) acc += w2[o * 64 + i] * h[pl][i];
  float y = fmaxf(acc * (g2[o] / SQ) + b2[o], 0.0f);
  out[(size_t)pt * 64 + o] = y;
}

// ---------------- farthest point sampling ----------------
// 1024 threads per batch (4 waves/SIMD for issue hiding), PPT = N/1024 so no
// register spills. Argmax carried as packed u64 key = bits(d)<<32 | ~idx
// (d >= 0 so float bits are order-monotonic; tie -> min idx = first
// occurrence, matching jnp.argmax). xyz staged in LDS; winner coords are
// broadcast-read from LDS, eliminating the dependent global center fetch.
// One barrier per iteration via parity double-buffered key scratch.
template <int N, int NP>
__global__ __launch_bounds__(1024, 1) void fps_kernel(
    const float* __restrict__ xyz, int* __restrict__ out) {
  constexpr int PPT = N / 1024;
  const int b = blockIdx.x, t = threadIdx.x;
  const float* xb = xyz + (size_t)b * N * 3;
  __shared__ float sx[N], sy[N], sz[N];
  __shared__ unsigned long long skey[2][16];
  for (int i = t; i < N; i += 1024) {
    sx[i] = xb[i * 3 + 0];
    sy[i] = xb[i * 3 + 1];
    sz[i] = xb[i * 3 + 2];
  }
  __syncthreads();
  float px[PPT], py[PPT], pz[PPT], dist[PPT];
  #pragma unroll
  for (int j = 0; j < PPT; ++j) {
    const int g = t * PPT + j;
    px[j] = sx[g];
    py[j] = sy[g];
    pz[j] = sz[g];
    dist[j] = 1e10f;
  }
  const int wid = t >> 6, lane = t & 63;
  int far = 0;
  float ccx = sx[0], ccy = sy[0], ccz = sz[0];
  for (int it = 0; it < NP; ++it) {
    if (t == 0) out[(size_t)b * NP + it] = far;
    // ---- distance update + local max-key over PPT ----
    unsigned long long bk = 0ull;
    #pragma unroll
    for (int j = 0; j < PPT; ++j) {
      const float dx = __fsub_rn(px[j], ccx);
      const float dy = __fsub_rn(py[j], ccy);
      const float dz = __fsub_rn(pz[j], ccz);
      const float d = __fadd_rn(__fadd_rn(__fmul_rn(dx, dx), __fmul_rn(dy, dy)),
                                __fmul_rn(dz, dz));
      const float nd = fminf(dist[j], d);
      dist[j] = nd;
      const unsigned long long key =
          ((unsigned long long)__float_as_uint(nd) << 32) |
          (unsigned long long)(unsigned)(~(unsigned)(t * PPT + j));
      bk = (key > bk) ? key : bk;
    }
    // ---- in-wave butterfly on packed keys ----
    #pragma unroll
    for (int m = 32; m >= 1; m >>= 1) {
      const unsigned long long ok = __shfl_xor(bk, m, 64);
      bk = (ok > bk) ? ok : bk;
    }
    const int p = it & 1;
    if (lane == 0) skey[p][wid] = bk;
    __syncthreads();
    // ---- every thread reduces the 16 wave winners (uniform result) ----
    unsigned long long wk = skey[p][0];
    #pragma unroll
    for (int q = 1; q < 16; ++q) {
      const unsigned long long k2 = skey[p][q];
      wk = (k2 > wk) ? k2 : wk;
    }
    far = (int)(~(unsigned)wk);
    ccx = sx[far]; ccy = sy[far]; ccz = sz[far];
  }
}

// ---------------- gather xyz by index ----------------
__global__ __launch_bounds__(256) void gatherxyz_kernel(
    const float* __restrict__ xyz, const int* __restrict__ idx,
    float* __restrict__ out, int sbits, int N) {
  const int id = blockIdx.x * 256 + threadIdx.x;
  const int b = id >> sbits;
  const int n = idx[id];
  out[(size_t)id * 3 + 0] = xyz[((size_t)b * N + n) * 3 + 0];
  out[(size_t)id * 3 + 1] = xyz[((size_t)b * N + n) * 3 + 1];
  out[(size_t)id * 3 + 2] = xyz[((size_t)b * N + n) * 3 + 2];
}

// ---------------- ball query: first 32 indices with d2 <= 1 ----------------
__global__ __launch_bounds__(256) void ball_kernel(
    const float* __restrict__ xyz, const float* __restrict__ ctr,
    int* __restrict__ out, int sbits, int N) {
  const int t = threadIdx.x;
  const int lane = t & 63, wid = t >> 6;
  const int wg = blockIdx.x * 4 + wid;   // global center id
  const int b = wg >> sbits;
  __shared__ int lists[4][32];
  const float cx = ctr[(size_t)wg * 3 + 0];
  const float cy = ctr[(size_t)wg * 3 + 1];
  const float cz = ctr[(size_t)wg * 3 + 2];
  const float an = __fadd_rn(__fadd_rn(__fmul_rn(cx, cx), __fmul_rn(cy, cy)),
                             __fmul_rn(cz, cz));
  int fill = 0;
  for (int ch = 0; ch < (N >> 6) && fill < 32; ++ch) {
    const int n = ch * 64 + lane;
    const float bx = xyz[((size_t)b * N + n) * 3 + 0];
    const float by = xyz[((size_t)b * N + n) * 3 + 1];
    const float bz = xyz[((size_t)b * N + n) * 3 + 2];
    const float bb = __fadd_rn(__fadd_rn(__fmul_rn(bx, bx), __fmul_rn(by, by)),
                               __fmul_rn(bz, bz));
    const float dot = __fadd_rn(__fadd_rn(__fmul_rn(cx, bx), __fmul_rn(cy, by)),
                                __fmul_rn(cz, bz));
    const float d2 = __fsub_rn(__fadd_rn(an, bb), __fmul_rn(2.0f, dot));
    const bool q = (d2 <= 1.0f);
    const unsigned long long mask = __ballot(q);
    if (q) {
      const int pos = fill + __popcll(mask & ((1ull << lane) - 1ull));
      if (pos < 32) lists[wid][pos] = n;
    }
    fill += (int)__popcll(mask);
  }
  __syncthreads();
  if (lane < 32) {
    int v = lists[wid][0];
    if (lane < fill) v = lists[wid][lane];
    out[(size_t)wg * 32 + lane] = v;
  }
}

// ---------------- grouped feature materialization ----------------
// row (chunk-local) -> [f[src]-f[ctr] (Cf) ; f[ctr] (Cf)]
__global__ __launch_bounds__(256) void groupmat_kernel(
    float* __restrict__ Xo, const float* __restrict__ f,
    const int* __restrict__ ball, const int* __restrict__ fps, int g0, int Cf,
    int c4bits, int sbits, int Npts) {
  const int id = blockIdx.x * 256 + threadIdx.x;
  const int c4mask = (1 << c4bits) - 1;
  const int row = id >> c4bits;
  const int col = (id & c4mask) * 4;
  const int gl = g0 + (row >> 5);
  const int k = row & 31;
  const int b = gl >> sbits;
  const int src = ball[(size_t)gl * 32 + k];
  const int ctr = fps[gl];
  const int C = Cf * 2;
  const float* fb = f + (size_t)b * Npts * Cf;
  float4 v;
  if (col < Cf) {
    const float4 a = *(const float4*)(fb + (size_t)src * Cf + col);
    const float4 c = *(const float4*)(fb + (size_t)ctr * Cf + col);
    v = make_float4(a.x - c.x, a.y - c.y, a.z - c.z, a.w - c.w);
  } else {
    v = *(const float4*)(fb + (size_t)ctr * Cf + (col - Cf));
  }
  *(float4*)(Xo + (size_t)row * C + col) = v;
}

// ---------------- generic 1x1 conv (GEMM) with BN/bias/ReLU epilogue -------
// Y[(m), o] = relu( (sum_i X[m,i] W[o,i] + bias[o]) * g[o]/sqrt(1+eps) + beta[o] )
__global__ __launch_bounds__(256) void conv_kernel(
    const float* __restrict__ X, const float* __restrict__ W,
    float* __restrict__ Y, int C, int O, const float* __restrict__ gamma,
    const float* __restrict__ beta, const float* __restrict__ bias, int relu) {
  __shared__ float Xs[16][132];
  __shared__ float Ws[16][132];
  const int t = threadIdx.x;
  const size_t m0 = (size_t)blockIdx.x * 128;
  const int o0 = blockIdx.y * 128;
  const int r0 = t >> 2;
  const int cq0 = (t & 3) * 4;
  const int mq = t & 15, nq = t >> 4;
  float acc[8][8];
  #pragma unroll
  for (int i = 0; i < 8; ++i)
    #pragma unroll
    for (int j = 0; j < 8; ++j) acc[i][j] = 0.0f;

  for (int kk = 0; kk < C; kk += 16) {
    const float4 xa = *(const float4*)(X + (m0 + r0) * C + kk + cq0);
    const float4 xb = *(const float4*)(X + (m0 + r0 + 64) * C + kk + cq0);
    const float4 wa = *(const float4*)(W + (size_t)(o0 + r0) * C + kk + cq0);
    const float4 wb = *(const float4*)(W + (size_t)(o0 + r0 + 64) * C + kk + cq0);
    __syncthreads();
    Xs[cq0 + 0][r0] = xa.x; Xs[cq0 + 1][r0] = xa.y;
    Xs[cq0 + 2][r0] = xa.z; Xs[cq0 + 3][r0] = xa.w;
    Xs[cq0 + 0][r0 + 64] = xb.x; Xs[cq0 + 1][r0 + 64] = xb.y;
    Xs[cq0 + 2][r0 + 64] = xb.z; Xs[cq0 + 3][r0 + 64] = xb.w;
    Ws[cq0 + 0][r0] = wa.x; Ws[cq0 + 1][r0] = wa.y;
    Ws[cq0 + 2][r0] = wa.z; Ws[cq0 + 3][r0] = wa.w;
    Ws[cq0 + 0][r0 + 64] = wb.x; Ws[cq0 + 1][r0 + 64] = wb.y;
    Ws[cq0 + 2][r0 + 64] = wb.z; Ws[cq0 + 3][r0 + 64] = wb.w;
    __syncthreads();
    #pragma unroll
    for (int k = 0; k < 16; ++k) {
      const float4 a0 = *(const float4*)&Xs[k][mq * 8];
      const float4 a1 = *(const float4*)&Xs[k][mq * 8 + 4];
      const float4 b0 = *(const float4*)&Ws[k][nq * 8];
      const float4 b1 = *(const float4*)&Ws[k][nq * 8 + 4];
      const float am[8] = {a0.x, a0.y, a0.z, a0.w, a1.x, a1.y, a1.z, a1.w};
      const float bm[8] = {b0.x, b0.y, b0.z, b0.w, b1.x, b1.y, b1.z, b1.w};
      #pragma unroll
      for (int i = 0; i < 8; ++i)
        #pragma unroll
        for (int j = 0; j < 8; ++j) acc[i][j] += am[i] * bm[j];
    }
  }

  const float SQ = sqrtf(1.0f + 1e-5f);
  float s[8], sh[8];
  #pragma unroll
  for (int j = 0; j < 8; ++j) {
    const int o = o0 + nq * 8 + j;
    const float sc = gamma ? (gamma[o] / SQ) : 1.0f;
    float bb = beta ? beta[o] : 0.0f;
    if (bias) bb = bb + bias[o] * sc;
    s[j] = sc; sh[j] = bb;
  }
  #pragma unroll
  for (int i = 0; i < 8; ++i) {
    float y[8];
    #pragma unroll
    for (int j = 0; j < 8; ++j) {
      float v = acc[i][j] * s[j] + sh[j];
      y[j] = relu ? fmaxf(v, 0.0f) : v;
    }
    const size_t off = (m0 + mq * 8 + i) * O + o0 + nq * 8;
    *(float4*)(Y + off) = make_float4(y[0], y[1], y[2], y[3]);
    *(float4*)(Y + off + 4) = make_float4(y[4], y[5], y[6], y[7]);
  }
}

// ---------------- segmented max over 32 samples ----------------
__global__ __launch_bounds__(256) void segmax_kernel(
    const float* __restrict__ Y, float* __restrict__ F, int O, int obits) {
  const int id = blockIdx.x * 256 + threadIdx.x;
  const int g = id >> obits;
  const int o = id & (O - 1);
  float m = -3.4e38f;
  #pragma unroll 8
  for (int k = 0; k < 32; ++k)
    m = fmaxf(m, Y[((size_t)g * 32 + k) * O + o]);
  F[(size_t)g * O + o] = m;
}

// ---------------- 3-NN search (stable, strict <) ----------------
__global__ __launch_bounds__(256) void nn3_kernel(
    const float* __restrict__ txyz, const float* __restrict__ sxyz,
    int* __restrict__ oi, float* __restrict__ ow, int s1bits, int S2) {
  __shared__ float ss[6144];
  const int t = threadIdx.x;
  const int row = blockIdx.x * 256 + t;
  const int b = row >> s1bits;
  for (int i = t; i < S2 * 3; i += 256) ss[i] = sxyz[(size_t)b * S2 * 3 + i];
  __syncthreads();
  const float ax = txyz[(size_t)row * 3 + 0];
  const float ay = txyz[(size_t)row * 3 + 1];
  const float az = txyz[(size_t)row * 3 + 2];
  const float an = __fadd_rn(__fadd_rn(__fmul_rn(ax, ax), __fmul_rn(ay, ay)),
                             __fmul_rn(az, az));
  float d0 = 3.4e38f, d1 = 3.4e38f, d2v = 3.4e38f;
  int i0 = 0, i1 = 0, i2 = 0;
  for (int j = 0; j < S2; ++j) {
    const float bx = ss[j * 3 + 0], by = ss[j * 3 + 1], bz = ss[j * 3 + 2];
    const float bb = __fadd_rn(__fadd_rn(__fmul_rn(bx, bx), __fmul_rn(by, by)),
                               __fmul_rn(bz, bz));
    const float dot = __fadd_rn(__fadd_rn(__fmul_rn(ax, bx), __fmul_rn(ay, by)),
                                __fmul_rn(az, bz));
    const float dd = __fsub_rn(__fadd_rn(an, bb), __fmul_rn(2.0f, dot));
    if (dd < d0) {
      d2v = d1; i2 = i1; d1 = d0; i1 = i0; d0 = dd; i0 = j;
    } else if (dd < d1) {
      d2v = d1; i2 = i1; d1 = dd; i1 = j;
    } else if (dd < d2v) {
      d2v = dd; i2 = j;
    }
  }
  const float r0 = 1.0f / (d0 + 1e-8f);
  const float r1 = 1.0f / (d1 + 1e-8f);
  const float r2 = 1.0f / (d2v + 1e-8f);
  const float sum = __fadd_rn(__fadd_rn(r0, r1), r2);
  oi[(size_t)row * 3 + 0] = i0;
  oi[(size_t)row * 3 + 1] = i1;
  oi[(size_t)row * 3 + 2] = i2;
  ow[(size_t)row * 3 + 0] = r0 / sum;
  ow[(size_t)row * 3 + 1] = r1 / sum;
  ow[(size_t)row * 3 + 2] = r2 / sum;
}

// ---------------- weighted 3-point interpolation into concat columns -------
__global__ __launch_bounds__(256) void interp_kernel(
    float* __restrict__ dst, int CT, int c0, const float* __restrict__ src,
    const int* __restrict__ idx, const float* __restrict__ w, int csbits,
    int s1bits, int S2) {
  const int id = blockIdx.x * 256 + threadIdx.x;
  const int row = id >> csbits;
  const int c4 = (id & ((1 << csbits) - 1)) * 4;
  const int Cs = 4 << csbits;
  const int b = row >> s1bits;
  const int j0 = idx[(size_t)row * 3 + 0];
  const int j1 = idx[(size_t)row * 3 + 1];
  const int j2 = idx[(size_t)row * 3 + 2];
  const float w0 = w[(size_t)row * 3 + 0];
  const float w1 = w[(size_t)row * 3 + 1];
  const float w2 = w[(size_t)row * 3 + 2];
  const float4 f0 = *(const float4*)(src + ((size_t)b * S2 + j0) * Cs + c4);
  const float4 f1 = *(const float4*)(src + ((size_t)b * S2 + j1) * Cs + c4);
  const float4 f2 = *(const float4*)(src + ((size_t)b * S2 + j2) * Cs + c4);
  float4 v;
  v.x = f0.x * w0 + f1.x * w1 + f2.x * w2;
  v.y = f0.y * w0 + f1.y * w1 + f2.y * w2;
  v.z = f0.z * w0 + f1.z * w1 + f2.z * w2;
  v.w = f0.w * w0 + f1.w * w1 + f2.w * w2;
  *(float4*)(dst + (size_t)row * CT + c0 + c4) = v;
}

// ---------------- copy columns into concat buffer ----------------
__global__ __launch_bounds__(256) void copycols_kernel(
    float* __restrict__ dst, int CT, int c0, const float* __restrict__ src,
    int csbits) {
  const int id = blockIdx.x * 256 + threadIdx.x;
  const int row = id >> csbits;
  const int c4 = (id & ((1 << csbits) - 1)) * 4;
  const int Cs = 4 << csbits;
  const float4 v = *(const float4*)(src + (size_t)row * Cs + c4);
  *(float4*)(dst + (size_t)row * CT + c0 + c4) = v;
}

// ---------------- final 128->8 conv + bias, point-major out ----------------
__global__ __launch_bounds__(256) void outfinal_kernel(
    const float* __restrict__ X, const float* __restrict__ Wt,
    const float* __restrict__ bias, float* __restrict__ out) {
  __shared__ float Xs[32][132];
  const int t = threadIdx.x;
  const int p0 = blockIdx.x * 32;
  #pragma unroll
  for (int q = 0; q < 4; ++q) {
    const int id = t + q * 256;
    const int r = id >> 5, c4 = (id & 31) * 4;
    const float4 v = *(const float4*)(X + (size_t)(p0 + r) * 128 + c4);
    Xs[r][c4 + 0] = v.x; Xs[r][c4 + 1] = v.y;
    Xs[r][c4 + 2] = v.z; Xs[r][c4 + 3] = v.w;
  }
  __syncthreads();
  const int p = t >> 3, o = t & 7;
  float acc = 0.0f;
  #pragma unroll 8
  for (int i = 0; i < 128; ++i) acc += Wt[o * 128 + i] * Xs[p][i];
  out[(size_t)(p0 + p) * 8 + o] = acc + bias[o];
}

// ---------------------------------------------------------------------------
extern "C" void kernel_launch(void* const* d_in, const int* in_sizes, int n_in,
                              void* d_out, int out_size, void* d_ws,
                              size_t ws_size, hipStream_t stream) {
  const float* x       = (const float*)d_in[0];
  const float* w_emb1  = (const float*)d_in[1];
  const float* g_emb1  = (const float*)d_in[2];
  const float* be_emb1 = (const float*)d_in[3];
  const float* w_emb2  = (const float*)d_in[4];
  const float* g_emb2  = (const float*)d_in[5];
  const float* be_emb2 = (const float*)d_in[6];
  const float* l0_w1 = (const float*)d_in[7];
  const float* l0_g1 = (const float*)d_in[8];
  const float* l0_b1 = (const float*)d_in[9];
  const float* l0_w2 = (const float*)d_in[10];
  const float* l0_g2 = (const float*)d_in[11];
  const float* l0_b2 = (const float*)d_in[12];
  const float* l1_w1 = (const float*)d_in[13];
  const float* l1_g1 = (const float*)d_in[14];
  const float* l1_b1 = (const float*)d_in[15];
  const float* l1_w2 = (const float*)d_in[16];
  const float* l1_g2 = (const float*)d_in[17];
  const float* l1_b2 = (const float*)d_in[18];
  const float* f0_w1 = (const float*)d_in[19];
  const float* f0_g1 = (const float*)d_in[20];
  const float* f0_b1 = (const float*)d_in[21];
  const float* f0_w2 = (const float*)d_in[22];
  const float* f0_g2 = (const float*)d_in[23];
  const float* f0_b2 = (const float*)d_in[24];
  const float* f1_w1 = (const float*)d_in[25];
  const float* f1_g1 = (const float*)d_in[26];
  const float* f1_b1 = (const float*)d_in[27];
  const float* f1_w2 = (const float*)d_in[28];
  const float* f1_g2 = (const float*)d_in[29];
  const float* f1_b2 = (const float*)d_in[30];
  const float* c1_w    = (const float*)d_in[31];
  const float* c1_bias = (const float*)d_in[32];
  const float* c1_g    = (const float*)d_in[33];
  const float* c1_beta = (const float*)d_in[34];
  const float* c2_w    = (const float*)d_in[35];
  const float* c2_bias = (const float*)d_in[36];
  const float* c2_g    = (const float*)d_in[37];
  const float* c2_beta = (const float*)d_in[38];
  const float* out_w    = (const float*)d_in[39];
  const float* out_bias = (const float*)d_in[40];

  if (ws_size < WS_NEED) return;  // cannot run without scratch

  char* ws = (char*)d_ws;
  float* feats0 = (float*)(ws + O_FEATS0);
  float* feats1 = (float*)(ws + O_FEATS1);
  float* feats2 = (float*)(ws + O_FEATS2);
  float* fp0out = (float*)(ws + O_FP0OUT);
  float* xyz1   = (float*)(ws + O_XYZ1);
  float* xyz2   = (float*)(ws + O_XYZ2);
  int*   fps1   = (int*)(ws + O_FPS1);
  int*   fps2   = (int*)(ws + O_FPS2);
  int*   ball1  = (int*)(ws + O_BALL1);
  int*   ball2  = (int*)(ws + O_BALL2);
  int*   nn0i   = (int*)(ws + O_NN0I);
  float* nn0w   = (float*)(ws + O_NN0W);
  int*   nn1i   = (int*)(ws + O_NN1I);
  float* nn1w   = (float*)(ws + O_NN1W);
  float* REG0   = (float*)(ws + O_REG0);
  float* REG1   = (float*)(ws + O_REG1);
  float* outp   = (float*)d_out;
  hipStream_t s = stream;

  // ---- embedding MLP: (B*8192, 64) ----
  emb_kernel<<<8192, 256, 0, s>>>(x, w_emb1, g_emb1, be_emb1, w_emb2, g_emb2,
                                  be_emb2, feats0);

  // ---- SA layer 1 ----
  fps_kernel<8192, 2048><<<4, 1024, 0, s>>>(x, fps1);
  gatherxyz_kernel<<<32, 256, 0, s>>>(x, fps1, xyz1, 11, 8192);
  ball_kernel<<<2048, 256, 0, s>>>(x, xyz1, ball1, 11, 8192);
  for (int c = 0; c < 2; ++c) {
    groupmat_kernel<<<16384, 256, 0, s>>>(REG0, feats0, ball1, fps1, c * 4096,
                                          64, 5, 11, 8192);
    conv_kernel<<<dim3(1024, 1), 256, 0, s>>>(REG0, l0_w1, REG1, 128, 128,
                                              l0_g1, l0_b1, nullptr, 1);
    conv_kernel<<<dim3(1024, 1), 256, 0, s>>>(REG1, l0_w2, REG0, 128, 128,
                                              l0_g2, l0_b2, nullptr, 1);
    segmax_kernel<<<2048, 256, 0, s>>>(REG0, feats1 + (size_t)c * 4096 * 128,
                                       128, 7);
  }

  // ---- SA layer 2 ----
  fps_kernel<2048, 1024><<<4, 1024, 0, s>>>(xyz1, fps2);
  gatherxyz_kernel<<<16, 256, 0, s>>>(xyz1, fps2, xyz2, 10, 2048);
  ball_kernel<<<1024, 256, 0, s>>>(xyz1, xyz2, ball2, 10, 2048);
  for (int c = 0; c < 2; ++c) {
    groupmat_kernel<<<16384, 256, 0, s>>>(REG0, feats1, ball2, fps2, c * 2048,
                                          128, 6, 10, 2048);
    conv_kernel<<<dim3(512, 2), 256, 0, s>>>(REG0, l1_w1, REG1, 256, 256,
                                             l1_g1, l1_b1, nullptr, 1);
    conv_kernel<<<dim3(512, 2), 256, 0, s>>>(REG1, l1_w2, REG0, 256, 256,
                                             l1_g2, l1_b2, nullptr, 1);
    segmax_kernel<<<2048, 256, 0, s>>>(REG0, feats2 + (size_t)c * 2048 * 256,
                                       256, 8);
  }

  // ---- feature propagation 0: 1024 -> 2048 points ----
  nn3_kernel<<<32, 256, 0, s>>>(xyz1, xyz2, nn0i, nn0w, 11, 1024);
  copycols_kernel<<<1024, 256, 0, s>>>(REG0, 384, 0, feats1, 5);
  interp_kernel<<<2048, 256, 0, s>>>(REG0, 384, 128, feats2, nn0i, nn0w, 6, 11,
                                     1024);
  conv_kernel<<<dim3(64, 2), 256, 0, s>>>(REG0, f0_w1, REG1, 384, 256, f0_g1,
                                          f0_b1, nullptr, 1);
  conv_kernel<<<dim3(64, 4), 256, 0, s>>>(REG1, f0_w2, fp0out, 256, 512, f0_g2,
                                          f0_b2, nullptr, 1);

  // ---- feature propagation 1 + head, chunked per batch ----
  nn3_kernel<<<128, 256, 0, s>>>(x, xyz1, nn1i, nn1w, 13, 2048);
  for (int b = 0; b < 4; ++b) {
    copycols_kernel<<<512, 256, 0, s>>>(REG0, 576, 0,
                                        feats0 + (size_t)b * 8192 * 64, 4);
    interp_kernel<<<4096, 256, 0, s>>>(REG0, 576, 64,
                                       fp0out + (size_t)b * 2048 * 512,
                                       nn1i + (size_t)b * 8192 * 3,
                                       nn1w + (size_t)b * 8192 * 3, 7, 13,
                                       2048);
    conv_kernel<<<dim3(64, 4), 256, 0, s>>>(REG0, f1_w1, REG1, 576, 512, f1_g1,
                                            f1_b1, nullptr, 1);
    conv_kernel<<<dim3(64, 8), 256, 0, s>>>(REG1, f1_w2, REG0, 512, 1024,
                                            f1_g2, f1_b2, nullptr, 1);
    conv_kernel<<<dim3(64, 4), 256, 0, s>>>(REG0, c1_w, REG1, 1024, 512, c1_g,
                                            c1_beta, c1_bias, 1);
    conv_kernel<<<dim3(64, 1), 256, 0, s>>>(REG1, c2_w, REG0, 512, 128, c2_g,
                                            c2_beta, c2_bias, 1);
    outfinal_kernel<<<256, 256, 0, s>>>(REG0, out_w, out_bias,
                                        outp + (size_t)b * 8192 * 8);
  }
}